// Round 5
// baseline (49.297 us; speedup 1.0000x reference)
//
#include <hip/hip_runtime.h>
#include <float.h>

// loss = (1/(E(E-1))) * sum_{i,j: t_i != t_j} relu(pred[i,t_j] - (f_own[j]-1)) / (N[t_i] N[t_j])
// Per class c (sorted thresholds + prefix sums): row i contribution from class c is
//   k*p - prefix[k], k = #{thr < p}, p = pred[i,c].
// 32-slot fixed search tree: levels 1-4 in registers (loop-invariant per thread),
// level 5 + prefix gather in LDS. Countable unrolled loop for pipelining.

#define CCLS 1000
#define PAD 64      // global slots per class (supports class count <= 63)
#define LSLOT 32    // LDS slots per class (fast path: count <= 31; else global fallback)
#define TPB 1024
#define CCH 250     // classes per chunk -> 4 chunks
#define NCH 4
#define NRBLK 128   // row blocks per chunk
#define LSTR 257    // LDS row stride: bank = (k + cc) & 31 -> <=2-way on all accesses

__global__ __launch_bounds__(1024) void k_prep(const int* __restrict__ target, int B,
        int* ncnt, float* invN, int* fill, float* scal, int* flags) {
    __shared__ int h[CCLS];
    __shared__ int esh, mx;
    int tid = threadIdx.x;
    if (tid < CCLS) h[tid] = 0;
    if (tid == 0) { esh = 0; mx = 0; }
    __syncthreads();
    for (int j = tid; j < B; j += TPB) atomicAdd(&h[target[j]], 1);
    __syncthreads();
    if (tid < CCLS) {
        int n = h[tid];
        ncnt[tid] = n;
        invN[tid] = n ? 1.0f / (float)n : 0.f;
        fill[tid] = 0;
        if (n) atomicAdd(&esh, 1);
        atomicMax(&mx, n);
    }
    __syncthreads();
    if (tid == 0) {
        scal[0] = (float)esh;   // E
        scal[1] = 0.f;          // accumulator
        flags[0] = 0;           // k_main completion counter
        flags[1] = (mx > LSLOT - 1) ? 1 : 0;  // overflow -> global fallback path
    }
}

__global__ void k_scatter(const float* __restrict__ pred, const int* __restrict__ target,
                          int* fill, float* thrP, int B) {
    int j = blockIdx.x * 256 + threadIdx.x;
    if (j >= B) return;
    int tj = target[j];
    float fo = pred[(size_t)j * CCLS + tj];  // f_own[j]
    int pos = atomicAdd(&fill[tj], 1);
    if (pos < PAD) thrP[tj * PAD + pos] = fo - 1.0f;
}

// wave-per-class rank sort + prefix via shuffles; writes all PAD slots (FLT_MAX pad, pref[cnt]=total)
__global__ __launch_bounds__(256) void k_sortpfx(const int* __restrict__ ncnt,
                                                 float* thrP, float* prefP) {
    int c = (blockIdx.x * 256 + threadIdx.x) >> 6;
    int lane = threadIdx.x & 63;
    if (c >= CCLS) return;
    int cnt = min(ncnt[c], PAD - 1);
    int base = c * PAD;
    float v = (lane < cnt) ? thrP[base + lane] : FLT_MAX;
    int rank = 0;
    float psum = 0.f, tot = 0.f;
    for (int k = 0; k < cnt; ++k) {
        float u = __shfl(v, k);
        bool sm = (u < v) || (u == v && k < lane);
        rank += sm ? 1 : 0;
        psum += sm ? u : 0.f;
        tot += u;
    }
    if (lane < cnt) { thrP[base + rank] = v; prefP[base + rank] = psum; }
    else           { thrP[base + lane] = FLT_MAX; prefP[base + lane] = tot; }
}

__global__ __launch_bounds__(TPB) void k_main(const float* __restrict__ pred,
        const int* __restrict__ target,
        const float* __restrict__ thrP, const float* __restrict__ prefP,
        const float* __restrict__ invN,
        float* scal, int* flags, float* __restrict__ out, int B, int RPB) {
    __shared__ float thrL[LSLOT][LSTR];
    __shared__ float prefL[LSLOT][LSTR];
    __shared__ float invNL[CCLS];
    __shared__ float redL[TPB / 64];

    const int tid = threadIdx.x;
    const int chunk = blockIdx.x / NRBLK;
    const int rblk = blockIdx.x % NRBLK;
    const int c0 = chunk * CCH;
    const int rbase = rblk * RPB;
    const int ovf = flags[1];

    for (int k = tid; k < CCLS; k += TPB) invNL[k] = invN[k];
    // stage transposed [k][cc]: coalesced-ish global reads, <=2-way LDS writes (bank=(k+cc)&31)
    for (int g = tid; g < CCH * LSLOT; g += TPB) {
        int cc = g >> 5, k = g & 31;
        thrL[k][cc] = thrP[(size_t)(c0 + cc) * PAD + k];
        prefL[k][cc] = prefP[(size_t)(c0 + cc) * PAD + k];
    }
    __syncthreads();

    const int rr = tid >> 8;        // 0..3: row phase
    const int cc = tid & 255;       // class within chunk
    const bool cvalid = cc < CCH;
    const int ccS = cvalid ? cc : 0;      // clamp so invalid lanes read real (finite) data
    const int c = c0 + ccS;
    const float invc = cvalid ? invNL[c] : 0.f;   // invalid lanes contribute 0

    const int rows = min(RPB, B - rbase);
    const int nit = (rows > rr) ? ((rows - rr + 3) >> 2) : 0;

    float acc = 0.f;
    if (!ovf) {
        // levels 1-4 of the fixed 32-slot search tree live in registers (loop-invariant)
        const float e15 = thrL[15][ccS];
        const float e7  = thrL[7][ccS],  e23 = thrL[23][ccS];
        const float e3  = thrL[3][ccS],  e11 = thrL[11][ccS];
        const float e19 = thrL[19][ccS], e27 = thrL[27][ccS];
        const float e1  = thrL[1][ccS],  e5  = thrL[5][ccS];
        const float e9  = thrL[9][ccS],  e13 = thrL[13][ccS];
        const float e17 = thrL[17][ccS], e21 = thrL[21][ccS];
        const float e25 = thrL[25][ccS], e29 = thrL[29][ccS];
#pragma unroll 4
        for (int it = 0; it < nit; ++it) {
            const int i = rbase + it * 4 + rr;
            const int ti = target[i];
            const float p = pred[(size_t)i * CCLS + c];
            const bool b1 = e15 < p;
            const float t2 = b1 ? e23 : e7;
            const bool b2 = t2 < p;
            const float t3 = b1 ? (b2 ? e27 : e19) : (b2 ? e11 : e3);
            const bool b3 = t3 < p;
            const float t4 = b1 ? (b2 ? (b3 ? e29 : e25) : (b3 ? e21 : e17))
                                : (b2 ? (b3 ? e13 : e9)  : (b3 ? e5  : e1));
            const bool b4 = t4 < p;
            int lo = (b1 ? 16 : 0) + (b2 ? 8 : 0) + (b3 ? 4 : 0) + (b4 ? 2 : 0);
            lo += (thrL[lo][ccS] < p) ? 1 : 0;        // level 5 (single LDS probe)
            const float contrib = (float)lo * p - prefL[lo][ccS];
            const float w = (c != ti) ? invc * invNL[ti] : 0.f;
            acc = fmaf(contrib, w, acc);
        }
    } else {
        // correctness fallback (class count > 31): 6-level search in global padded segment
        const float* seg = thrP + (size_t)c * PAD;
        const float* pseg = prefP + (size_t)c * PAD;
        for (int it = 0; it < nit; ++it) {
            const int i = rbase + it * 4 + rr;
            const int ti = target[i];
            const float p = pred[(size_t)i * CCLS + c];
            int lo = 0;
#pragma unroll
            for (int s = 32; s; s >>= 1) lo += (seg[lo + s - 1] < p) ? s : 0;
            const float contrib = (float)lo * p - pseg[lo];
            const float w = (c != ti) ? invc * invNL[ti] : 0.f;
            acc = fmaf(contrib, w, acc);
        }
    }

    for (int o = 32; o; o >>= 1) acc += __shfl_down(acc, o);
    if ((tid & 63) == 0) redL[tid >> 6] = acc;
    __syncthreads();
    if (tid == 0) {
        float ssum = 0.f;
#pragma unroll
        for (int k = 0; k < TPB / 64; ++k) ssum += redL[k];
        atomicAdd(&scal[1], ssum);
        __threadfence();
        int done = atomicAdd(&flags[0], 1);
        if (done == (int)gridDim.x - 1) {   // last block finalizes (fused k_final)
            float tot = atomicAdd(&scal[1], 0.f);
            float E = scal[0];
            out[0] = tot / (E * (E - 1.0f));
        }
    }
}

extern "C" void kernel_launch(void* const* d_in, const int* in_sizes, int n_in,
                              void* d_out, int out_size, void* d_ws, size_t ws_size,
                              hipStream_t stream) {
    const float* pred = (const float*)d_in[0];
    const int* target = (const int*)d_in[1];
    const int B = in_sizes[1];  // 12288

    char* ws = (char*)d_ws;
    int* ncnt    = (int*)(ws + 0);        // 1000 ints
    float* invN  = (float*)(ws + 4096);   // 1000 floats
    int* fill    = (int*)(ws + 8192);     // 1000 ints
    float* scal  = (float*)(ws + 12288);  // [0]=E, [1]=acc
    int* flags   = (int*)(ws + 12352);    // [0]=counter, [1]=overflow
    float* thrP  = (float*)(ws + 16384);            // 1000*64 floats (256KB)
    float* prefP = (float*)(ws + 16384 + 262144);   // 1000*64 floats (256KB)

    const int gb = (B + 255) / 256;
    const int RPB = (B + NRBLK - 1) / NRBLK;

    k_prep<<<1, TPB, 0, stream>>>(target, B, ncnt, invN, fill, scal, flags);
    k_scatter<<<gb, 256, 0, stream>>>(pred, target, fill, thrP, B);
    k_sortpfx<<<(CCLS * 64 + 255) / 256, 256, 0, stream>>>(ncnt, thrP, prefP);
    k_main<<<NCH * NRBLK, TPB, 0, stream>>>(pred, target, thrP, prefP, invN,
                                            scal, flags, (float*)d_out, B, RPB);
}